// Round 5
// baseline (632.196 us; speedup 1.0000x reference)
//
#include <hip/hip_runtime.h>
#include <hip/hip_bf16.h>

#define H 128
#define NSTEPS 8
#define DT_MAXF 0.125f
#define WAVES 4
#define PPW 16            // points per wave (one 16x16 MFMA M-tile)
#define PPB (WAVES*PPW)   // 64 points per block

typedef __attribute__((ext_vector_type(8))) short short8;   // 8 bf16 MFMA A/B frag
typedef __attribute__((ext_vector_type(4))) float floatx4;  // MFMA C/D frag

__device__ __forceinline__ float fast_tanh(float x) {
    float e = __builtin_amdgcn_exp2f(x * 2.8853900817779268f); // 2*log2(e)
    float r = __builtin_amdgcn_rcpf(e + 1.0f);
    return 1.0f - 2.0f * r;
}
__device__ __forceinline__ unsigned f2bf(float x) {           // fp32 -> bf16 bits, RNE (init-time)
    unsigned u = __float_as_uint(x);
    return (u + 0x7FFFu + ((u >> 16) & 1u)) >> 16;
}
__device__ __forceinline__ unsigned pk2(float a, float b) {   // packed bf16 cvt via union pun
    union { __hip_bfloat162 h; unsigned u; } U;
    U.h = __float22bfloat162_rn(make_float2(a, b));
    return U.u;
}
__device__ __forceinline__ short8 pack_bf8(const float* z) {
    union { unsigned u[4]; short8 s; } U;
    U.u[0] = pk2(z[0], z[1]); U.u[1] = pk2(z[2], z[3]);
    U.u[2] = pk2(z[4], z[5]); U.u[3] = pk2(z[6], z[7]);
    return U.s;
}
// select a[r] for r in 0..3 WITHOUT dynamic register indexing (3 cndmask, not scratch!)
__device__ __forceinline__ float sel4(float a0, float a1, float a2, float a3, int r) {
    float v = a0;
    v = (r == 1) ? a1 : v;
    v = (r == 2) ? a2 : v;
    v = (r == 3) ? a3 : v;
    return v;
}

__global__ __launch_bounds__(256, 2)
void velwarp(const float* __restrict__ code, const float* __restrict__ pos,
             const float* __restrict__ t1g, const float* __restrict__ t2g,
             const float* __restrict__ W1, const float* __restrict__ b1,
             const float* __restrict__ W2, const float* __restrict__ b2,
             const float* __restrict__ W3, const float* __restrict__ b3,
             float* __restrict__ out, int N)
{
    // LDS ~40.9KB: Wbuf 32K (W1 fp32 during init, then W2 bf16 frag-linear) + tables
    __shared__ __align__(16) unsigned Wbuf[H*H/2];      // 32KB
    __shared__ __align__(16) float W1xc[4][H];          // W1xc[c][u] = W1[64+c][u]
    __shared__ __align__(16) float W3s[H][4];           // [u][o], o==3 pad
    __shared__ __align__(16) float x4[WAVES][PPW][4];   // per-wave xyzt of each point
    __shared__ __align__(16) float defS[WAVES][PPW][12];// deform 3x3 (pad to 12)

    const int tid = threadIdx.x;
    const int w   = tid >> 6;
    const int L   = tid & 63;
    const int m   = L & 15;      // point row for z1-prep; C/D col-in-tile
    const int q   = L >> 4;      // k-quad for A/B frags; C/D row group = q*4+r
    const int pb  = blockIdx.x * PPB + w * PPW;
    const int r_  = m;           // writer row when < 4
    const bool wr = (r_ < 4);
    const int mm  = q*4 + r_;    // writer's point index in wave (valid when wr)

    // ---- stage W1 rows [0:64) as fp32 into Wbuf; small tables
    {
        const float4* s4 = (const float4*)W1;
        float4* d4 = (float4*)Wbuf;
        #pragma unroll 4
        for (int i = tid; i < (64*H)/4; i += 256) d4[i] = s4[i];
    }
    for (int idx = tid; idx < 4*H; idx += 256) {
        int c = idx >> 7, u = idx & (H-1);
        W1xc[c][u] = W1[(64 + c)*H + u];
    }
    for (int idx = tid; idx < 4*H; idx += 256) {
        int u = idx >> 2, o = idx & 3;
        W3s[u][o] = (o < 3) ? W3[u*3 + o] : 0.0f;
    }
    __syncthreads();

    // ---- base1[s][j] = b1[u] + code[point m] . W1[:64, u],  u = s*32 + q*8 + j
    float base1[4][8];
    {
        #pragma unroll
        for (int s = 0; s < 4; ++s) {
            float4 ba = *(const float4*)&b1[s*32 + q*8];
            float4 bb = *(const float4*)&b1[s*32 + q*8 + 4];
            base1[s][0]=ba.x; base1[s][1]=ba.y; base1[s][2]=ba.z; base1[s][3]=ba.w;
            base1[s][4]=bb.x; base1[s][5]=bb.y; base1[s][6]=bb.z; base1[s][7]=bb.w;
        }
        const float* Ws = (const float*)Wbuf;
        const float* crow = code + (size_t)(pb + m) * 64;
        for (int i = 0; i < 64; ++i) {
            float c = crow[i];
            #pragma unroll
            for (int s = 0; s < 4; ++s) {
                const float* wrp = &Ws[i*H + s*32 + q*8];
                float4 wa = *(const float4*)wrp;
                float4 wb = *(const float4*)(wrp + 4);
                base1[s][0] = fmaf(c, wa.x, base1[s][0]);
                base1[s][1] = fmaf(c, wa.y, base1[s][1]);
                base1[s][2] = fmaf(c, wa.z, base1[s][2]);
                base1[s][3] = fmaf(c, wa.w, base1[s][3]);
                base1[s][4] = fmaf(c, wb.x, base1[s][4]);
                base1[s][5] = fmaf(c, wb.y, base1[s][5]);
                base1[s][6] = fmaf(c, wb.z, base1[s][6]);
                base1[s][7] = fmaf(c, wb.w, base1[s][7]);
            }
        }
    }
    __syncthreads();

    // ---- pack W2 -> bf16 fragment-linear (RNE)
    for (int ch = tid; ch < 2048; ch += 256) {
        int ln = ch & 63, ts = ch >> 6;
        int s = ts & 3, t = ts >> 2;
        int k0 = s*32 + (ln >> 4)*8, n = t*16 + (ln & 15);
        unsigned pk0 = f2bf(W2[(k0+0)*H + n]) | (f2bf(W2[(k0+1)*H + n]) << 16);
        unsigned pk1 = f2bf(W2[(k0+2)*H + n]) | (f2bf(W2[(k0+3)*H + n]) << 16);
        unsigned pk2_ = f2bf(W2[(k0+4)*H + n]) | (f2bf(W2[(k0+5)*H + n]) << 16);
        unsigned pk3 = f2bf(W2[(k0+6)*H + n]) | (f2bf(W2[(k0+7)*H + n]) << 16);
        ((uint4*)Wbuf)[ch] = make_uint4(pk0, pk1, pk2_, pk3);
    }

    // ---- writer-lane scalar state (plain scalars: NO dynamically-indexed arrays)
    float px_=0.f, py_=0.f, pz_=0.f, tc_=0.f, off_=0.f, dt_=0.f;
    if (wr) {
        int p = pb + mm;
        px_ = pos[p*3+0]; py_ = pos[p*3+1]; pz_ = pos[p*3+2];
        float t1v = t1g[p];
        tc_ = t1v; off_ = t1v - t2g[p];
        *(float4*)&x4[w][mm][0] = make_float4(px_, py_, pz_, tc_);
        #pragma unroll
        for (int j = 0; j < 9; ++j) defS[w][mm][j] = (j==0||j==4||j==8) ? 1.0f : 0.0f;
    }
    const float b30 = b3[0], b31 = b3[1], b32 = b3[2];
    float b2reg[8];
    #pragma unroll
    for (int t = 0; t < 8; ++t) b2reg[t] = b2[t*16 + m];
    __syncthreads();

    const short8* Bf = (const short8*)Wbuf;

    for (int step = 0; step < NSTEPS; ++step) {
        // ======== eval A: h1 a-frags built directly in registers ========
        short8 af[4];
        {
            float4 xt = *(const float4*)&x4[w][m][0];
            #pragma unroll
            for (int s = 0; s < 4; ++s) {
                const int u0 = s*32 + q*8;
                float wx[8], wy[8], wz[8], wt[8], h[8];
                *(float4*)&wx[0] = *(const float4*)&W1xc[0][u0]; *(float4*)&wx[4] = *(const float4*)&W1xc[0][u0+4];
                *(float4*)&wy[0] = *(const float4*)&W1xc[1][u0]; *(float4*)&wy[4] = *(const float4*)&W1xc[1][u0+4];
                *(float4*)&wz[0] = *(const float4*)&W1xc[2][u0]; *(float4*)&wz[4] = *(const float4*)&W1xc[2][u0+4];
                *(float4*)&wt[0] = *(const float4*)&W1xc[3][u0]; *(float4*)&wt[4] = *(const float4*)&W1xc[3][u0+4];
                #pragma unroll
                for (int j = 0; j < 8; ++j) {
                    float zz = base1[s][j];
                    zz = fmaf(xt.x, wx[j], zz);
                    zz = fmaf(xt.y, wy[j], zz);
                    zz = fmaf(xt.z, wz[j], zz);
                    zz = fmaf(xt.w, wt[j], zz);
                    h[j] = fast_tanh(zz);
                }
                af[s] = pack_bf8(h);
            }
        }
        float velp[3][4];
        #pragma unroll
        for (int r = 0; r < 4; ++r) { velp[0][r]=0.f; velp[1][r]=0.f; velp[2][r]=0.f; }
        #pragma unroll
        for (int t = 0; t < 8; ++t) {
            float b2n = b2reg[t];
            floatx4 acc = {b2n, b2n, b2n, b2n};          // b2 folded into acc init
            #pragma unroll
            for (int s = 0; s < 4; ++s)
                acc = __builtin_amdgcn_mfma_f32_16x16x32_bf16(af[s], Bf[(t*4+s)*64 + L], acc, 0, 0, 0);
            float4 w3 = *(const float4*)&W3s[t*16 + m][0];
            #pragma unroll
            for (int r = 0; r < 4; ++r) {
                float h2 = fast_tanh(acc[r]);
                velp[0][r] = fmaf(h2, w3.x, velp[0][r]);
                velp[1][r] = fmaf(h2, w3.y, velp[1][r]);
                velp[2][r] = fmaf(h2, w3.z, velp[2][r]);
            }
        }
        #pragma unroll
        for (int mk = 1; mk < 16; mk <<= 1) {
            #pragma unroll
            for (int o = 0; o < 3; ++o)
                #pragma unroll
                for (int r = 0; r < 4; ++r)
                    velp[o][r] += __shfl_xor(velp[o][r], mk, 64);
        }
        if (wr) {
            dt_ = copysignf(fminf(fabsf(off_), DT_MAXF), off_);
            float hd = 0.5f * dt_;
            float vx = sel4(velp[0][0], velp[0][1], velp[0][2], velp[0][3], r_) + b30;
            float vy = sel4(velp[1][0], velp[1][1], velp[1][2], velp[1][3], r_) + b31;
            float vz = sel4(velp[2][0], velp[2][1], velp[2][2], velp[2][3], r_) + b32;
            *(float4*)&x4[w][mm][0] = make_float4(px_ - hd*vx, py_ - hd*vy, pz_ - hd*vz, tc_ - hd);
        }
        asm volatile("s_waitcnt lgkmcnt(0)" ::: "memory");

        // ======== eval B: h1 + 3 tangent a-frags in registers ========
        short8 afB[4], df0[4], df1[4], df2[4];
        {
            float4 xt = *(const float4*)&x4[w][m][0];
            #pragma unroll
            for (int s = 0; s < 4; ++s) {
                const int u0 = s*32 + q*8;
                float wx[8], wy[8], wz[8], wt[8], h[8], d0[8], d1[8], d2[8];
                *(float4*)&wx[0] = *(const float4*)&W1xc[0][u0]; *(float4*)&wx[4] = *(const float4*)&W1xc[0][u0+4];
                *(float4*)&wy[0] = *(const float4*)&W1xc[1][u0]; *(float4*)&wy[4] = *(const float4*)&W1xc[1][u0+4];
                *(float4*)&wz[0] = *(const float4*)&W1xc[2][u0]; *(float4*)&wz[4] = *(const float4*)&W1xc[2][u0+4];
                *(float4*)&wt[0] = *(const float4*)&W1xc[3][u0]; *(float4*)&wt[4] = *(const float4*)&W1xc[3][u0+4];
                #pragma unroll
                for (int j = 0; j < 8; ++j) {
                    float zz = base1[s][j];
                    zz = fmaf(xt.x, wx[j], zz);
                    zz = fmaf(xt.y, wy[j], zz);
                    zz = fmaf(xt.z, wz[j], zz);
                    zz = fmaf(xt.w, wt[j], zz);
                    float hh = fast_tanh(zz);
                    float sd = fmaf(-hh, hh, 1.0f);
                    h[j]  = hh;
                    d0[j] = sd * wx[j];
                    d1[j] = sd * wy[j];
                    d2[j] = sd * wz[j];
                }
                afB[s] = pack_bf8(h);
                df0[s] = pack_bf8(d0);
                df1[s] = pack_bf8(d1);
                df2[s] = pack_bf8(d2);
            }
        }
        float velq[3][4], Jp[9][4];   // Jp[o*3+i][r] — ALL indices compile-time constant
        #pragma unroll
        for (int r = 0; r < 4; ++r) {
            velq[0][r] = velq[1][r] = velq[2][r] = 0.0f;
            #pragma unroll
            for (int oi = 0; oi < 9; ++oi) Jp[oi][r] = 0.0f;
        }
        #pragma unroll
        for (int t = 0; t < 8; ++t) {
            float b2n = b2reg[t];
            floatx4 a0 = {b2n,b2n,b2n,b2n};
            floatx4 a1 = {0.f,0.f,0.f,0.f}, a2 = {0.f,0.f,0.f,0.f}, a3 = {0.f,0.f,0.f,0.f};
            #pragma unroll
            for (int s = 0; s < 4; ++s) {
                short8 b = Bf[(t*4+s)*64 + L];
                a0 = __builtin_amdgcn_mfma_f32_16x16x32_bf16(afB[s], b, a0, 0, 0, 0);
                a1 = __builtin_amdgcn_mfma_f32_16x16x32_bf16(df0[s], b, a1, 0, 0, 0);
                a2 = __builtin_amdgcn_mfma_f32_16x16x32_bf16(df1[s], b, a2, 0, 0, 0);
                a3 = __builtin_amdgcn_mfma_f32_16x16x32_bf16(df2[s], b, a3, 0, 0, 0);
            }
            float4 w3 = *(const float4*)&W3s[t*16 + m][0];
            #pragma unroll
            for (int r = 0; r < 4; ++r) {
                float h2 = fast_tanh(a0[r]);
                float s2 = fmaf(-h2, h2, 1.0f);
                velq[0][r] = fmaf(h2, w3.x, velq[0][r]);
                velq[1][r] = fmaf(h2, w3.y, velq[1][r]);
                velq[2][r] = fmaf(h2, w3.z, velq[2][r]);
                float dd0 = s2*a1[r], dd1 = s2*a2[r], dd2 = s2*a3[r];
                Jp[0][r] = fmaf(dd0, w3.x, Jp[0][r]);
                Jp[1][r] = fmaf(dd1, w3.x, Jp[1][r]);
                Jp[2][r] = fmaf(dd2, w3.x, Jp[2][r]);
                Jp[3][r] = fmaf(dd0, w3.y, Jp[3][r]);
                Jp[4][r] = fmaf(dd1, w3.y, Jp[4][r]);
                Jp[5][r] = fmaf(dd2, w3.y, Jp[5][r]);
                Jp[6][r] = fmaf(dd0, w3.z, Jp[6][r]);
                Jp[7][r] = fmaf(dd1, w3.z, Jp[7][r]);
                Jp[8][r] = fmaf(dd2, w3.z, Jp[8][r]);
            }
        }
        #pragma unroll
        for (int mk = 1; mk < 16; mk <<= 1) {
            #pragma unroll
            for (int r = 0; r < 4; ++r) {
                velq[0][r] += __shfl_xor(velq[0][r], mk, 64);
                velq[1][r] += __shfl_xor(velq[1][r], mk, 64);
                velq[2][r] += __shfl_xor(velq[2][r], mk, 64);
                #pragma unroll
                for (int oi = 0; oi < 9; ++oi)
                    Jp[oi][r] += __shfl_xor(Jp[oi][r], mk, 64);
            }
        }
        // writer-lane state update: sel4 extraction, no dynamic indexing
        if (wr) {
            float vx = sel4(velq[0][0], velq[0][1], velq[0][2], velq[0][3], r_) + b30;
            float vy = sel4(velq[1][0], velq[1][1], velq[1][2], velq[1][3], r_) + b31;
            float vz = sel4(velq[2][0], velq[2][1], velq[2][2], velq[2][3], r_) + b32;
            float J[9];
            #pragma unroll
            for (int oi = 0; oi < 9; ++oi)
                J[oi] = sel4(Jp[oi][0], Jp[oi][1], Jp[oi][2], Jp[oi][3], r_);
            float D[9], nd[9];
            #pragma unroll
            for (int j = 0; j < 9; ++j) D[j] = defS[w][mm][j];
            #pragma unroll
            for (int o = 0; o < 3; ++o)
                #pragma unroll
                for (int c = 0; c < 3; ++c)
                    nd[o*3+c] = D[o*3+c] - dt_*(J[o*3+0]*D[0*3+c] + J[o*3+1]*D[1*3+c] + J[o*3+2]*D[2*3+c]);
            #pragma unroll
            for (int j = 0; j < 9; ++j) defS[w][mm][j] = nd[j];
            px_ = fmaf(-dt_, vx, px_);
            py_ = fmaf(-dt_, vy, py_);
            pz_ = fmaf(-dt_, vz, pz_);
            tc_  -= dt_;
            off_ -= dt_;
            *(float4*)&x4[w][mm][0] = make_float4(px_, py_, pz_, tc_);
        }
        asm volatile("s_waitcnt lgkmcnt(0)" ::: "memory");
    }

    // ---- output: xyz then deform
    if (wr) {
        int p = pb + mm;
        out[p*3+0] = px_; out[p*3+1] = py_; out[p*3+2] = pz_;
        float* o9 = out + (size_t)N*3 + (size_t)p*9;
        #pragma unroll
        for (int j = 0; j < 9; ++j) o9[j] = defS[w][mm][j];
    }
}

extern "C" void kernel_launch(void* const* d_in, const int* in_sizes, int n_in,
                              void* d_out, int out_size, void* d_ws, size_t ws_size,
                              hipStream_t stream) {
    const float* code = (const float*)d_in[0];
    const float* pos  = (const float*)d_in[1];
    const float* t1   = (const float*)d_in[2];
    const float* t2   = (const float*)d_in[3];
    const float* W1   = (const float*)d_in[4];
    const float* b1   = (const float*)d_in[5];
    const float* W2   = (const float*)d_in[6];
    const float* b2   = (const float*)d_in[7];
    const float* W3   = (const float*)d_in[8];
    const float* b3   = (const float*)d_in[9];
    float* out = (float*)d_out;
    const int N = in_sizes[1] / 3;           // 131072
    const int blocks = N / PPB;              // 2048
    velwarp<<<blocks, 256, 0, stream>>>(code, pos, t1, t2, W1, b1, W2, b2, W3, b3, out, N);
}

// Round 6
// 567.928 us; speedup vs baseline: 1.1132x; 1.1132x over previous
//
#include <hip/hip_runtime.h>
#include <hip/hip_bf16.h>

#define H 128
#define NSTEPS 8
#define DT_MAXF 0.125f
#define WAVES 4
#define PPW 16            // points per wave (one 16x16 MFMA M-tile)
#define PPB (WAVES*PPW)   // 64 points per block

typedef __attribute__((ext_vector_type(8))) short short8;   // 8 bf16 MFMA A/B frag
typedef __attribute__((ext_vector_type(4))) float floatx4;  // MFMA C/D frag

__device__ __forceinline__ float fast_tanh(float x) {
    float e = __builtin_amdgcn_exp2f(x * 2.8853900817779268f); // 2*log2(e)
    float r = __builtin_amdgcn_rcpf(e + 1.0f);
    return 1.0f - 2.0f * r;
}
__device__ __forceinline__ unsigned f2bf(float x) {           // fp32 -> bf16 bits, RNE (init-time)
    unsigned u = __float_as_uint(x);
    return (u + 0x7FFFu + ((u >> 16) & 1u)) >> 16;
}
__device__ __forceinline__ unsigned pk2(float a, float b) {   // packed bf16 cvt via union pun
    union { __hip_bfloat162 h; unsigned u; } U;
    U.h = __float22bfloat162_rn(make_float2(a, b));
    return U.u;
}
__device__ __forceinline__ short8 pack_bf8(const float* z) {
    union { unsigned u[4]; short8 s; } U;
    U.u[0] = pk2(z[0], z[1]); U.u[1] = pk2(z[2], z[3]);
    U.u[2] = pk2(z[4], z[5]); U.u[3] = pk2(z[6], z[7]);
    return U.s;
}
// select a[r] for r in 0..3 WITHOUT dynamic register indexing (3 cndmask)
__device__ __forceinline__ float sel4(float a0, float a1, float a2, float a3, int r) {
    float v = a0;
    v = (r == 1) ? a1 : v;
    v = (r == 2) ? a2 : v;
    v = (r == 3) ? a3 : v;
    return v;
}

__global__ __launch_bounds__(256, 2)
void velwarp(const float* __restrict__ code, const float* __restrict__ pos,
             const float* __restrict__ t1g, const float* __restrict__ t2g,
             const float* __restrict__ W1, const float* __restrict__ b1,
             const float* __restrict__ W2, const float* __restrict__ b2,
             const float* __restrict__ W3, const float* __restrict__ b3,
             float* __restrict__ out, int N)
{
    // LDS ~41.5KB: Wbuf 32K (W1 fp32 during init, then W2 bf16 frag-linear) + tables
    __shared__ __align__(16) unsigned Wbuf[H*H/2];      // 32KB
    __shared__ __align__(16) float W1xc[4][H];          // W1xc[c][u] = W1[64+c][u]
    __shared__ __align__(16) float W3s[H][4];           // [u][o], o==3 pad
    __shared__ float b2s[H];
    __shared__ __align__(16) float x4[WAVES][PPW][4];   // per-wave xyzt of each point
    __shared__ __align__(16) float defS[WAVES][PPW][12];// deform 3x3 (pad to 12)

    const int tid = threadIdx.x;
    const int w   = tid >> 6;
    const int L   = tid & 63;
    const int m   = L & 15;      // point row for z1-prep; C/D col-in-tile
    const int q   = L >> 4;      // k-quad for A/B frags; C/D row group = q*4+r
    const int pb  = blockIdx.x * PPB + w * PPW;
    const int r_  = m;           // writer row when < 4
    const bool wr = (r_ < 4);
    const int mm  = q*4 + r_;    // writer's point index in wave (valid when wr)

    // ---- stage W1 rows [0:64) as fp32 into Wbuf; small tables
    {
        const float4* s4 = (const float4*)W1;
        float4* d4 = (float4*)Wbuf;
        #pragma unroll 4
        for (int i = tid; i < (64*H)/4; i += 256) d4[i] = s4[i];
    }
    for (int idx = tid; idx < 4*H; idx += 256) {
        int c = idx >> 7, u = idx & (H-1);
        W1xc[c][u] = W1[(64 + c)*H + u];
    }
    for (int idx = tid; idx < 4*H; idx += 256) {
        int u = idx >> 2, o = idx & 3;
        W3s[u][o] = (o < 3) ? W3[u*3 + o] : 0.0f;
    }
    if (tid < H) b2s[tid] = b2[tid];
    __syncthreads();

    // ---- base1[s][j] = b1[u] + code[point m] . W1[:64, u],  u = s*32 + q*8 + j
    float base1[4][8];
    {
        #pragma unroll
        for (int s = 0; s < 4; ++s) {
            float4 ba = *(const float4*)&b1[s*32 + q*8];
            float4 bb = *(const float4*)&b1[s*32 + q*8 + 4];
            base1[s][0]=ba.x; base1[s][1]=ba.y; base1[s][2]=ba.z; base1[s][3]=ba.w;
            base1[s][4]=bb.x; base1[s][5]=bb.y; base1[s][6]=bb.z; base1[s][7]=bb.w;
        }
        const float* Ws = (const float*)Wbuf;
        const float* crow = code + (size_t)(pb + m) * 64;
        for (int i = 0; i < 64; ++i) {
            float c = crow[i];
            #pragma unroll
            for (int s = 0; s < 4; ++s) {
                const float* wrp = &Ws[i*H + s*32 + q*8];
                float4 wa = *(const float4*)wrp;
                float4 wb = *(const float4*)(wrp + 4);
                base1[s][0] = fmaf(c, wa.x, base1[s][0]);
                base1[s][1] = fmaf(c, wa.y, base1[s][1]);
                base1[s][2] = fmaf(c, wa.z, base1[s][2]);
                base1[s][3] = fmaf(c, wa.w, base1[s][3]);
                base1[s][4] = fmaf(c, wb.x, base1[s][4]);
                base1[s][5] = fmaf(c, wb.y, base1[s][5]);
                base1[s][6] = fmaf(c, wb.z, base1[s][6]);
                base1[s][7] = fmaf(c, wb.w, base1[s][7]);
            }
        }
    }
    __syncthreads();

    // ---- pack W2 -> bf16 fragment-linear (RNE)
    for (int ch = tid; ch < 2048; ch += 256) {
        int ln = ch & 63, ts = ch >> 6;
        int s = ts & 3, t = ts >> 2;
        int k0 = s*32 + (ln >> 4)*8, n = t*16 + (ln & 15);
        unsigned pk0 = f2bf(W2[(k0+0)*H + n]) | (f2bf(W2[(k0+1)*H + n]) << 16);
        unsigned pk1 = f2bf(W2[(k0+2)*H + n]) | (f2bf(W2[(k0+3)*H + n]) << 16);
        unsigned pk2_ = f2bf(W2[(k0+4)*H + n]) | (f2bf(W2[(k0+5)*H + n]) << 16);
        unsigned pk3 = f2bf(W2[(k0+6)*H + n]) | (f2bf(W2[(k0+7)*H + n]) << 16);
        ((uint4*)Wbuf)[ch] = make_uint4(pk0, pk1, pk2_, pk3);
    }

    // ---- writer-lane scalar state (plain scalars)
    float px_=0.f, py_=0.f, pz_=0.f, tc_=0.f, off_=0.f, dt_=0.f;
    if (wr) {
        int p = pb + mm;
        px_ = pos[p*3+0]; py_ = pos[p*3+1]; pz_ = pos[p*3+2];
        float t1v = t1g[p];
        tc_ = t1v; off_ = t1v - t2g[p];
        *(float4*)&x4[w][mm][0] = make_float4(px_, py_, pz_, tc_);
        #pragma unroll
        for (int j = 0; j < 9; ++j) defS[w][mm][j] = (j==0||j==4||j==8) ? 1.0f : 0.0f;
    }
    const float b30 = b3[0], b31 = b3[1], b32 = b3[2];
    __syncthreads();

    const short8* Bf = (const short8*)Wbuf;

    for (int step = 0; step < NSTEPS; ++step) {
        // ======== eval A: s-outer, 8 N-tile accumulators stay resident (AGPR) ========
        floatx4 accA[8];
        #pragma unroll
        for (int t = 0; t < 8; ++t) {
            float b2n = b2s[t*16 + m];
            accA[t] = (floatx4){b2n, b2n, b2n, b2n};
        }
        {
            float4 xt = *(const float4*)&x4[w][m][0];
            #pragma unroll
            for (int s = 0; s < 4; ++s) {
                const int u0 = s*32 + q*8;
                float h[8];
                #pragma unroll
                for (int jh = 0; jh < 8; jh += 4) {
                    float4 wx = *(const float4*)&W1xc[0][u0+jh];
                    float4 wy = *(const float4*)&W1xc[1][u0+jh];
                    float4 wz = *(const float4*)&W1xc[2][u0+jh];
                    float4 wt = *(const float4*)&W1xc[3][u0+jh];
                    h[jh+0] = fast_tanh(fmaf(xt.w,wt.x, fmaf(xt.z,wz.x, fmaf(xt.y,wy.x, fmaf(xt.x,wx.x, base1[s][jh+0])))));
                    h[jh+1] = fast_tanh(fmaf(xt.w,wt.y, fmaf(xt.z,wz.y, fmaf(xt.y,wy.y, fmaf(xt.x,wx.y, base1[s][jh+1])))));
                    h[jh+2] = fast_tanh(fmaf(xt.w,wt.z, fmaf(xt.z,wz.z, fmaf(xt.y,wy.z, fmaf(xt.x,wx.z, base1[s][jh+2])))));
                    h[jh+3] = fast_tanh(fmaf(xt.w,wt.w, fmaf(xt.z,wz.w, fmaf(xt.y,wy.w, fmaf(xt.x,wx.w, base1[s][jh+3])))));
                }
                short8 af = pack_bf8(h);
                #pragma unroll
                for (int t = 0; t < 8; ++t)
                    accA[t] = __builtin_amdgcn_mfma_f32_16x16x32_bf16(af, Bf[(t*4+s)*64 + L], accA[t], 0, 0, 0);
            }
        }
        float velp[3][4];
        #pragma unroll
        for (int r = 0; r < 4; ++r) { velp[0][r]=0.f; velp[1][r]=0.f; velp[2][r]=0.f; }
        #pragma unroll
        for (int t = 0; t < 8; ++t) {
            float4 w3 = *(const float4*)&W3s[t*16 + m][0];
            #pragma unroll
            for (int r = 0; r < 4; ++r) {
                float h2 = fast_tanh(accA[t][r]);
                velp[0][r] = fmaf(h2, w3.x, velp[0][r]);
                velp[1][r] = fmaf(h2, w3.y, velp[1][r]);
                velp[2][r] = fmaf(h2, w3.z, velp[2][r]);
            }
        }
        #pragma unroll
        for (int mk = 1; mk < 16; mk <<= 1) {
            #pragma unroll
            for (int o = 0; o < 3; ++o)
                #pragma unroll
                for (int r = 0; r < 4; ++r)
                    velp[o][r] += __shfl_xor(velp[o][r], mk, 64);
        }
        if (wr) {
            dt_ = copysignf(fminf(fabsf(off_), DT_MAXF), off_);
            float hd = 0.5f * dt_;
            float vx = sel4(velp[0][0], velp[0][1], velp[0][2], velp[0][3], r_) + b30;
            float vy = sel4(velp[1][0], velp[1][1], velp[1][2], velp[1][3], r_) + b31;
            float vz = sel4(velp[2][0], velp[2][1], velp[2][2], velp[2][3], r_) + b32;
            *(float4*)&x4[w][mm][0] = make_float4(px_ - hd*vx, py_ - hd*vy, pz_ - hd*vz, tc_ - hd);
        }
        asm volatile("s_waitcnt lgkmcnt(0)" ::: "memory");

        // ======== eval B: s-outer; 4 chains x 8 N-tiles resident (128 AGPR floats) ========
        floatx4 aB0[8], aB1[8], aB2[8], aB3[8];
        #pragma unroll
        for (int t = 0; t < 8; ++t) {
            float b2n = b2s[t*16 + m];
            aB0[t] = (floatx4){b2n, b2n, b2n, b2n};
            aB1[t] = (floatx4){0.f, 0.f, 0.f, 0.f};
            aB2[t] = (floatx4){0.f, 0.f, 0.f, 0.f};
            aB3[t] = (floatx4){0.f, 0.f, 0.f, 0.f};
        }
        {
            float4 xt = *(const float4*)&x4[w][m][0];
            #pragma unroll
            for (int s = 0; s < 4; ++s) {
                const int u0 = s*32 + q*8;
                float h[8], d0[8], d1[8], d2[8];
                #pragma unroll
                for (int jh = 0; jh < 8; jh += 4) {
                    float4 wx = *(const float4*)&W1xc[0][u0+jh];
                    float4 wy = *(const float4*)&W1xc[1][u0+jh];
                    float4 wz = *(const float4*)&W1xc[2][u0+jh];
                    float4 wt = *(const float4*)&W1xc[3][u0+jh];
                    #pragma unroll
                    for (int c4 = 0; c4 < 4; ++c4) {
                        float wxv = (c4==0)?wx.x:(c4==1)?wx.y:(c4==2)?wx.z:wx.w;
                        float wyv = (c4==0)?wy.x:(c4==1)?wy.y:(c4==2)?wy.z:wy.w;
                        float wzv = (c4==0)?wz.x:(c4==1)?wz.y:(c4==2)?wz.z:wz.w;
                        float wtv = (c4==0)?wt.x:(c4==1)?wt.y:(c4==2)?wt.z:wt.w;
                        int j = jh + c4;
                        float zz = fmaf(xt.w,wtv, fmaf(xt.z,wzv, fmaf(xt.y,wyv, fmaf(xt.x,wxv, base1[s][j]))));
                        float hh = fast_tanh(zz);
                        float sd = fmaf(-hh, hh, 1.0f);
                        h[j]  = hh;
                        d0[j] = sd * wxv;
                        d1[j] = sd * wyv;
                        d2[j] = sd * wzv;
                    }
                }
                short8 f0 = pack_bf8(h);
                short8 f1 = pack_bf8(d0);
                short8 f2 = pack_bf8(d1);
                short8 f3 = pack_bf8(d2);
                #pragma unroll
                for (int t = 0; t < 8; ++t) {
                    short8 b = Bf[(t*4+s)*64 + L];
                    aB0[t] = __builtin_amdgcn_mfma_f32_16x16x32_bf16(f0, b, aB0[t], 0, 0, 0);
                    aB1[t] = __builtin_amdgcn_mfma_f32_16x16x32_bf16(f1, b, aB1[t], 0, 0, 0);
                    aB2[t] = __builtin_amdgcn_mfma_f32_16x16x32_bf16(f2, b, aB2[t], 0, 0, 0);
                    aB3[t] = __builtin_amdgcn_mfma_f32_16x16x32_bf16(f3, b, aB3[t], 0, 0, 0);
                }
            }
        }
        float velq[3][4], Jp[9][4];   // all indices compile-time constant
        #pragma unroll
        for (int r = 0; r < 4; ++r) {
            velq[0][r] = velq[1][r] = velq[2][r] = 0.0f;
            #pragma unroll
            for (int oi = 0; oi < 9; ++oi) Jp[oi][r] = 0.0f;
        }
        #pragma unroll
        for (int t = 0; t < 8; ++t) {
            float4 w3 = *(const float4*)&W3s[t*16 + m][0];
            #pragma unroll
            for (int r = 0; r < 4; ++r) {
                float h2 = fast_tanh(aB0[t][r]);
                float s2 = fmaf(-h2, h2, 1.0f);
                velq[0][r] = fmaf(h2, w3.x, velq[0][r]);
                velq[1][r] = fmaf(h2, w3.y, velq[1][r]);
                velq[2][r] = fmaf(h2, w3.z, velq[2][r]);
                float dd0 = s2*aB1[t][r], dd1 = s2*aB2[t][r], dd2 = s2*aB3[t][r];
                Jp[0][r] = fmaf(dd0, w3.x, Jp[0][r]);
                Jp[1][r] = fmaf(dd1, w3.x, Jp[1][r]);
                Jp[2][r] = fmaf(dd2, w3.x, Jp[2][r]);
                Jp[3][r] = fmaf(dd0, w3.y, Jp[3][r]);
                Jp[4][r] = fmaf(dd1, w3.y, Jp[4][r]);
                Jp[5][r] = fmaf(dd2, w3.y, Jp[5][r]);
                Jp[6][r] = fmaf(dd0, w3.z, Jp[6][r]);
                Jp[7][r] = fmaf(dd1, w3.z, Jp[7][r]);
                Jp[8][r] = fmaf(dd2, w3.z, Jp[8][r]);
            }
        }
        #pragma unroll
        for (int mk = 1; mk < 16; mk <<= 1) {
            #pragma unroll
            for (int r = 0; r < 4; ++r) {
                velq[0][r] += __shfl_xor(velq[0][r], mk, 64);
                velq[1][r] += __shfl_xor(velq[1][r], mk, 64);
                velq[2][r] += __shfl_xor(velq[2][r], mk, 64);
                #pragma unroll
                for (int oi = 0; oi < 9; ++oi)
                    Jp[oi][r] += __shfl_xor(Jp[oi][r], mk, 64);
            }
        }
        if (wr) {
            float vx = sel4(velq[0][0], velq[0][1], velq[0][2], velq[0][3], r_) + b30;
            float vy = sel4(velq[1][0], velq[1][1], velq[1][2], velq[1][3], r_) + b31;
            float vz = sel4(velq[2][0], velq[2][1], velq[2][2], velq[2][3], r_) + b32;
            float J[9];
            #pragma unroll
            for (int oi = 0; oi < 9; ++oi)
                J[oi] = sel4(Jp[oi][0], Jp[oi][1], Jp[oi][2], Jp[oi][3], r_);
            float D[9], nd[9];
            #pragma unroll
            for (int j = 0; j < 9; ++j) D[j] = defS[w][mm][j];
            #pragma unroll
            for (int o = 0; o < 3; ++o)
                #pragma unroll
                for (int c = 0; c < 3; ++c)
                    nd[o*3+c] = D[o*3+c] - dt_*(J[o*3+0]*D[0*3+c] + J[o*3+1]*D[1*3+c] + J[o*3+2]*D[2*3+c]);
            #pragma unroll
            for (int j = 0; j < 9; ++j) defS[w][mm][j] = nd[j];
            px_ = fmaf(-dt_, vx, px_);
            py_ = fmaf(-dt_, vy, py_);
            pz_ = fmaf(-dt_, vz, pz_);
            tc_  -= dt_;
            off_ -= dt_;
            *(float4*)&x4[w][mm][0] = make_float4(px_, py_, pz_, tc_);
        }
        asm volatile("s_waitcnt lgkmcnt(0)" ::: "memory");
    }

    // ---- output: xyz then deform
    if (wr) {
        int p = pb + mm;
        out[p*3+0] = px_; out[p*3+1] = py_; out[p*3+2] = pz_;
        float* o9 = out + (size_t)N*3 + (size_t)p*9;
        #pragma unroll
        for (int j = 0; j < 9; ++j) o9[j] = defS[w][mm][j];
    }
}

extern "C" void kernel_launch(void* const* d_in, const int* in_sizes, int n_in,
                              void* d_out, int out_size, void* d_ws, size_t ws_size,
                              hipStream_t stream) {
    const float* code = (const float*)d_in[0];
    const float* pos  = (const float*)d_in[1];
    const float* t1   = (const float*)d_in[2];
    const float* t2   = (const float*)d_in[3];
    const float* W1   = (const float*)d_in[4];
    const float* b1   = (const float*)d_in[5];
    const float* W2   = (const float*)d_in[6];
    const float* b2   = (const float*)d_in[7];
    const float* W3   = (const float*)d_in[8];
    const float* b3   = (const float*)d_in[9];
    float* out = (float*)d_out;
    const int N = in_sizes[1] / 3;           // 131072
    const int blocks = N / PPB;              // 2048
    velwarp<<<blocks, 256, 0, stream>>>(code, pos, t1, t2, W1, b1, W2, b2, W3, b3, out, N);
}